// Round 12
// baseline (41.863 us; speedup 1.0000x reference)
//
#include <hip/hip_runtime.h>

// QuerySpecificClusterModel: B=256 samples, n=64 points, d=768.
// Round 12: single-kernel everything. The 1-block finalize_kernel cost a
// launch gap + ~1-2us dispatch for 1KB of reduction; fold it into the fused
// kernel via decoupled-reduction: partials -> __threadfence (device-scope
// release; per-XCD L2s non-coherent, G16) -> atomicAdd counter (device-scope,
// m20); last block (old==255) acquires + reduces in wave 0. Counter zeroed
// per replay by a hipMemsetAsync node (capturable). No spins -> no hang.
// Gram + MST tail identical to round 11.

#define NPTS 64
#define DIM 768
#define CH 128
#define NCH 6
#define NT 512
#define BIGF 1e9f
#define PGS 68

typedef __attribute__((ext_vector_type(8))) __bf16 bf16x8;
typedef __attribute__((ext_vector_type(4))) float f32x4;
typedef __attribute__((ext_vector_type(8))) unsigned short us8;

// cross-lane LDS visibility fence within one wave (guide rule #18)
__device__ __forceinline__ void lds_fence() {
  asm volatile("s_waitcnt lgkmcnt(0)" ::: "memory");
  __builtin_amdgcn_sched_barrier(0);
}

// ---- exact 3-way bf16 split: x == h + m + l ----
__device__ __forceinline__ void split3(float x, unsigned short& h,
                                       unsigned short& m, unsigned short& l) {
  unsigned u = __float_as_uint(x);
  unsigned rb = (u + 0x7FFFu + ((u >> 16) & 1u)) & 0xFFFF0000u;   // RNE
  h = (unsigned short)(rb >> 16);
  float r1 = x - __uint_as_float(rb);                              // exact
  unsigned u1 = __float_as_uint(r1);
  unsigned rb1 = (u1 + 0x7FFFu + ((u1 >> 16) & 1u)) & 0xFFFF0000u;
  m = (unsigned short)(rb1 >> 16);
  float r2 = r1 - __uint_as_float(rb1);                            // exact
  l = (unsigned short)(__float_as_uint(r2) >> 16);                 // exact
}

// stage one chunk (scale by q, split3, swizzled LDS write). Hb = Hml[buf].
__device__ __forceinline__ void stage_chunk(
    unsigned short (*Hb)[NPTS][CH], const float4 (&pva)[2][2],
    const float4 (&qv)[2], int row0, int gran) {
  #pragma unroll
  for (int rr = 0; rr < 2; ++rr) {
    const int row = row0 + (rr << 5);
    float xs[8];
    xs[0] = pva[rr][0].x * qv[0].x; xs[1] = pva[rr][0].y * qv[0].y;
    xs[2] = pva[rr][0].z * qv[0].z; xs[3] = pva[rr][0].w * qv[0].w;
    xs[4] = pva[rr][1].x * qv[1].x; xs[5] = pva[rr][1].y * qv[1].y;
    xs[6] = pva[rr][1].z * qv[1].z; xs[7] = pva[rr][1].w * qv[1].w;
    us8 uh, um, ul;
    #pragma unroll
    for (int e = 0; e < 8; ++e) {
      unsigned short hh, mm, ll;
      split3(xs[e], hh, mm, ll);
      uh[e] = hh; um[e] = mm; ul[e] = ll;
    }
    const int p = gran ^ (row & 15);
    *reinterpret_cast<us8*>(&Hb[0][row][p << 3]) = uh;
    *reinterpret_cast<us8*>(&Hb[1][row][p << 3]) = um;
    *reinterpret_cast<us8*>(&Hb[2][row][p << 3]) = ul;
  }
}

// one chunk of MFMA work for this wave. Hb = Hml[buf].
__device__ __forceinline__ void mfma_chunk(
    const unsigned short (*Hb)[NPTS][CH], f32x4 (&acc)[2][2],
    int R, int C, int ksub, int lrow, int lhi) {
  #pragma unroll 1
  for (int ss = 0; ss < 2; ++ss) {
    const int s = ksub + (ss << 1);
    const int p = ((s << 2) + lhi) ^ lrow;
    bf16x8 fa[3][2], fb[3][2];
    #pragma unroll
    for (int v = 0; v < 3; ++v)
      #pragma unroll
      for (int tb = 0; tb < 2; ++tb) {
        const int row = (R << 5) + (tb << 4) + lrow;
        fa[v][tb] = *reinterpret_cast<const bf16x8*>(&Hb[v][row][p << 3]);
      }
    if (R != C) {
      #pragma unroll
      for (int v = 0; v < 3; ++v)
        #pragma unroll
        for (int tb = 0; tb < 2; ++tb) {
          const int row = (C << 5) + (tb << 4) + lrow;
          fb[v][tb] = *reinterpret_cast<const bf16x8*>(&Hb[v][row][p << 3]);
        }
    } else {
      #pragma unroll
      for (int v = 0; v < 3; ++v)
        #pragma unroll
        for (int tb = 0; tb < 2; ++tb) fb[v][tb] = fa[v][tb];
    }
    #pragma unroll
    for (int ti = 0; ti < 2; ++ti)
      #pragma unroll
      for (int tj = 0; tj < 2; ++tj) {
        acc[ti][tj] = __builtin_amdgcn_mfma_f32_16x16x32_bf16(fa[0][ti], fb[0][tj], acc[ti][tj], 0, 0, 0); // hh
        acc[ti][tj] = __builtin_amdgcn_mfma_f32_16x16x32_bf16(fa[0][ti], fb[1][tj], acc[ti][tj], 0, 0, 0); // hm
        acc[ti][tj] = __builtin_amdgcn_mfma_f32_16x16x32_bf16(fa[1][ti], fb[0][tj], acc[ti][tj], 0, 0, 0); // mh
        acc[ti][tj] = __builtin_amdgcn_mfma_f32_16x16x32_bf16(fa[1][ti], fb[1][tj], acc[ti][tj], 0, 0, 0); // mm
        acc[ti][tj] = __builtin_amdgcn_mfma_f32_16x16x32_bf16(fa[0][ti], fb[2][tj], acc[ti][tj], 0, 0, 0); // hl
        acc[ti][tj] = __builtin_amdgcn_mfma_f32_16x16x32_bf16(fa[2][ti], fb[0][tj], acc[ti][tj], 0, 0, 0); // lh
      }
  }
}

#define ISSUE_P(PV, cix) do {                                       \
    const int off_ = (cix) * CH;                                    \
    PV[0][0] = *(const float4*)(pr0 + off_);                        \
    PV[0][1] = *(const float4*)(pr0 + off_ + 4);                    \
    PV[1][0] = *(const float4*)(pr1 + off_);                        \
    PV[1][1] = *(const float4*)(pr1 + off_ + 4);                    \
  } while (0)

#define ISSUE_Q(QV, cix) do {                                       \
    const int off_ = (cix) * CH;                                    \
    QV[0] = *(const float4*)(qr + off_);                            \
    QV[1] = *(const float4*)(qr + off_ + 4);                        \
  } while (0)

// ===== fused kernel: MFMA Gram -> distances -> MST -> last-block finalize ===
__global__ __launch_bounds__(NT) void fused_kernel(
    const float* __restrict__ q,      // [256,768]
    const float* __restrict__ psg,    // [256,64,768]
    const int*   __restrict__ labels, // [256,64]
    float* simS_o, float* disS_o, int* simC_o, int* errC_o,
    int* counter, float* out)
{
  __shared__ __align__(16) unsigned short Hml[2][3][NPTS][CH]; // 96 KB dbuf
  __shared__ __align__(16) float PG[NPTS * PGS];
  __shared__ float diagf[NPTS];
  __shared__ __align__(16) int cls[NPTS];
  __shared__ __align__(16) int comp_s[NPTS];
  __shared__ unsigned bw_s[NPTS], bfl_s[NPTS];
  __shared__ int ptr_s[NPTS], lab_s[NPTS];
  __shared__ __align__(8) unsigned long long ekey_s[NPTS];
  __shared__ int ecnt_s;

  const int b = blockIdx.x;
  const int t = threadIdx.x;
  const int w = t >> 6;
  const int l = t & 63;

  const float* qb = q + (size_t)b * DIM;
  const float* pb = psg + (size_t)b * NPTS * DIM;

  const int row0 = t >> 4;
  const int gran = t & 15;
  const float* pr0 = pb + (size_t)row0 * DIM + (gran << 3);
  const float* pr1 = pr0 + 32 * DIM;
  const float* qr  = qb + (gran << 3);

  const int rw = w >> 1;
  const int R = rw >> 1, C = rw & 1;
  const int ksub = w & 1;
  const int lrow = l & 15;
  const int lhi  = l >> 4;

  f32x4 acc[2][2];
  {
    f32x4 z = {0.f, 0.f, 0.f, 0.f};
    acc[0][0] = z; acc[0][1] = z; acc[1][0] = z; acc[1][1] = z;
  }

  // two NAMED prefetch sets (static indexing; rule #20)
  float4 pvaA[2][2], pvaB[2][2], qv[2];

  ISSUE_P(pvaA, 0);
  ISSUE_Q(qv, 0);
  ISSUE_P(pvaB, 1);
  stage_chunk(Hml[0], pvaA, qv, row0, gran);
  __syncthreads();

  #pragma unroll 1
  for (int cc = 0; cc < 3; ++cc) {
    if (cc < 2) ISSUE_P(pvaA, 2 * cc + 2);
    ISSUE_Q(qv, 2 * cc + 1);
    mfma_chunk(Hml[0], acc, R, C, ksub, lrow, lhi);
    stage_chunk(Hml[1], pvaB, qv, row0, gran);
    __syncthreads();
    if (cc < 2) {
      ISSUE_P(pvaB, 2 * cc + 3);
      ISSUE_Q(qv, 2 * cc + 2);
    }
    mfma_chunk(Hml[1], acc, R, C, ksub, lrow, lhi);
    if (cc < 2) stage_chunk(Hml[0], pvaA, qv, row0, gran);
    __syncthreads();
  }

  // ---- K-split pair reduce: odd wave -> LDS, even wave adds ----
  if (w & 1) {
    float* dst = PG + (rw << 10);
    #pragma unroll
    for (int ti = 0; ti < 2; ++ti)
      #pragma unroll
      for (int tj = 0; tj < 2; ++tj)
        *reinterpret_cast<f32x4*>(dst + (((ti << 1) + tj) << 8) + (l << 2)) = acc[ti][tj];
  }
  __syncthreads();
  if (!(w & 1)) {
    const float* src = PG + (rw << 10);
    #pragma unroll
    for (int ti = 0; ti < 2; ++ti)
      #pragma unroll
      for (int tj = 0; tj < 2; ++tj)
        acc[ti][tj] += *reinterpret_cast<const f32x4*>(src + (((ti << 1) + tj) << 8) + (l << 2));
  }
  __syncthreads();
  if (!(w & 1)) {
    #pragma unroll
    for (int ti = 0; ti < 2; ++ti)
      #pragma unroll
      for (int tj = 0; tj < 2; ++tj)
        #pragma unroll
        for (int reg = 0; reg < 4; ++reg) {
          const int grow = (R << 5) + (ti << 4) + (lhi << 2) + reg;
          const int gcol = (C << 5) + (tj << 4) + lrow;
          PG[grow * PGS + gcol] = acc[ti][tj][reg];
        }
  }
  __syncthreads();

  // ---- distances in place ----
  if (t < NPTS) diagf[t] = PG[t * PGS + t];
  __syncthreads();
  {
    const int r  = t >> 3;
    const int c0 = (t & 7) << 3;
    const float dr = diagf[r];
    #pragma unroll
    for (int e = 0; e < 8; ++e) {
      const int cc = c0 + e;
      const float gg = PG[r * PGS + cc];
      float d2 = dr + diagf[cc] - 2.f * gg;
      d2 = fmaxf(d2, 0.f);
      PG[r * PGS + cc] = (d2 > 0.f) ? sqrtf(d2) : 0.f;
    }
  }
  __syncthreads();
  if (w != 0) return;            // wave 0 runs the MST tail

  // ============== MST clustering (single wave, lane l = point l) ============
  float drow[64];
  #pragma unroll
  for (int v4 = 0; v4 < 16; ++v4) {
    f32x4 x = *reinterpret_cast<const f32x4*>(&PG[l * PGS + (v4 << 2)]);
    drow[v4 * 4 + 0] = x[0]; drow[v4 * 4 + 1] = x[1];
    drow[v4 * 4 + 2] = x[2]; drow[v4 * 4 + 3] = x[3];
  }
  int tl = labels[b * NPTS + l];

  unsigned long long sMask = 0ull;
  int kcnt = 0;
  #pragma unroll
  for (int v = 0; v < 8; ++v) {
    unsigned long long mv = __ballot(tl == v);
    kcnt += (mv != 0ull) ? 1 : 0;
    if (tl == v) sMask = mv;
  }
  int simC = __popcll(sMask);
  const int merges = NPTS - kcnt;

  float simS = 0.f, disS = 0.f;
  #pragma unroll
  for (int j = 0; j < NPTS; ++j) {
    bool sim = (sMask >> j) & 1ull;
    simS += sim ? drow[j] : 0.f;
    disS += sim ? 0.f : drow[j];
  }

  comp_s[l] = l; lab_s[l] = l;
  if (l == 0) ecnt_s = 0;
  lds_fence();

  // ---- Boruvka with early exits ----
  #pragma unroll 1
  for (int rd = 0; rd < 6; ++rd) {
    bw_s[l] = 0xFFFFFFFFu; bfl_s[l] = 0xFFFFFFFFu;
    lds_fence();
    const int myc = comp_s[l];
    float bv = BIGF; int bj = 64;
    #pragma unroll
    for (int jc = 0; jc < 16; ++jc) {
      int4 c4 = *reinterpret_cast<const int4*>(&comp_s[jc << 2]);
      int cj[4] = {c4.x, c4.y, c4.z, c4.w};
      #pragma unroll
      for (int e = 0; e < 4; ++e) {
        const int j = (jc << 2) + e;
        bool ok = (cj[e] != myc) && (drow[j] < bv);
        bv = ok ? drow[j] : bv;
        bj = ok ? j : bj;
      }
    }
    if (bj < 64) atomicMin(&bw_s[myc], __float_as_uint(bv));
    lds_fence();
    unsigned bwc = bw_s[myc];
    if (bj < 64 && __float_as_uint(bv) == bwc)
      atomicMin(&bfl_s[myc], (unsigned)((l << 6) | bj));
    lds_fence();
    const bool isroot = (myc == l);
    const unsigned rw_ = bw_s[l];
    const unsigned rf  = bfl_s[l];
    int hook = l;
    if (isroot && rw_ != 0xFFFFFFFFu)
      hook = comp_s[rf & 63];
    ptr_s[l] = isroot ? hook : myc;
    lds_fence();
    if (isroot && hook != l) {
      const int pd = ptr_s[hook];
      if (pd == l && l < hook) {
        ptr_s[l] = l;
      } else {
        int slot = atomicAdd(&ecnt_s, 1);
        ekey_s[slot & 63] = ((unsigned long long)rw_ << 32) | (unsigned long long)rf;
      }
    }
    lds_fence();
    #pragma unroll 1
    for (int jj = 0; jj < 6; ++jj) {
      int pp = ptr_s[l];
      int p2 = ptr_s[pp & 63];
      if (__ballot(p2 != pp) == 0ull) break;
      ptr_s[l] = p2;
    }
    lds_fence();
    const int newc = ptr_s[l];
    comp_s[l] = newc;
    lds_fence();
    const int base = __shfl(newc, 0);
    if (__ballot(newc != base) == 0ull) break;
  }

  // ---- edge selection: keep the `merges` smallest (w, flat) keys ----
  const int ec = ecnt_s;
  const bool ehave = (l < ec);
  const unsigned long long my = ehave ? ekey_s[l] : ~0ull;
  int rank = 0;
  #pragma unroll 7
  for (int j = 0; j < 63; ++j) {
    unsigned long long kj = ekey_s[j];
    rank += (j < ec && kj < my) ? 1 : 0;
  }
  const bool kept = ehave && (rank < merges);
  const int eu = (int)((my >> 6) & 63);
  const int ev = (int)(my & 63);

  // ---- label propagation on kept edges ----
  #pragma unroll 1
  for (int iter = 0; iter < 64; ++iter) {
    int m = 0; bool ch = false;
    if (kept) {
      int lu = lab_s[eu], lv = lab_s[ev];
      m = min(lu, lv);
      ch = (m < lu) || (m < lv);
    }
    if (__ballot(ch) == 0ull) break;
    if (ch) {
      atomicMin(&lab_s[eu], m);
      atomicMin(&lab_s[ev], m);
    }
    lds_fence();
  }
  lds_fence();
  const int cl = lab_s[l];

  cls[l] = cl;
  lds_fence();
  unsigned long long cMask = 0ull;
  const int4* cp = reinterpret_cast<const int4*>(cls);
  #pragma unroll 4
  for (int jq = 0; jq < 16; ++jq) {
    int4 c4 = cp[jq];
    cMask |= ((unsigned long long)(c4.x == cl)) << (jq * 4 + 0);
    cMask |= ((unsigned long long)(c4.y == cl)) << (jq * 4 + 1);
    cMask |= ((unsigned long long)(c4.z == cl)) << (jq * 4 + 2);
    cMask |= ((unsigned long long)(c4.w == cl)) << (jq * 4 + 3);
  }
  int ec2 = __popcll(cMask ^ sMask);

  #pragma unroll
  for (int off = 32; off; off >>= 1) {
    simS += __shfl_xor(simS, off);
    disS += __shfl_xor(disS, off);
    simC += __shfl_xor(simC, off);
    ec2  += __shfl_xor(ec2, off);
  }
  if (l == 0) {
    simS_o[b] = simS; disS_o[b] = disS;
    simC_o[b] = simC; errC_o[b] = ec2;
  }

  // ---- decoupled finalize: last block reduces all partials ----
  __threadfence();                         // release partials device-wide
  int old = 0;
  if (l == 0) old = atomicAdd(counter, 1); // device-scope (m20)
  old = __shfl(old, 0);
  if (old == 255) {
    __threadfence();                       // acquire others' partials
    double ss = 0.0, dd = 0.0, sc = 0.0, ee = 0.0;
    #pragma unroll
    for (int r = 0; r < 4; ++r) {
      int i = (r << 6) + l;                // fixed order -> deterministic
      ss += (double)simS_o[i];
      dd += (double)disS_o[i];
      sc += (double)simC_o[i];
      ee += (double)errC_o[i];
    }
    #pragma unroll
    for (int off = 32; off; off >>= 1) {
      ss += __shfl_xor(ss, off);
      dd += __shfl_xor(dd, off);
      sc += __shfl_xor(sc, off);
      ee += __shfl_xor(ee, off);
    }
    if (l == 0) {
      const double total = 256.0 * 4096.0;
      out[0] = (float)(ee / 256.0 + 0.5 * (ss / sc - dd / (total - sc)));
    }
  }
}

extern "C" void kernel_launch(void* const* d_in, const int* in_sizes, int n_in,
                              void* d_out, int out_size, void* d_ws, size_t ws_size,
                              hipStream_t stream) {
  const float* q      = (const float*)d_in[0];
  const float* psg    = (const float*)d_in[1];
  const int*   labels = (const int*)d_in[2];
  float* out = (float*)d_out;

  float* simS = (float*)d_ws;            // [256]
  float* disS = simS + 256;              // [256]
  int*   simC = (int*)(disS + 256);      // [256]
  int*   errC = simC + 256;              // [256]
  int*   counter = errC + 256;           // [1] — zeroed every replay below

  hipMemsetAsync(counter, 0, sizeof(int), stream);
  fused_kernel<<<256, NT, 0, stream>>>(q, psg, labels, simS, disS, simC, errC,
                                       counter, out);
}

// Round 13
// 32.130 us; speedup vs baseline: 1.3029x; 1.3029x over previous
//
#include <hip/hip_runtime.h>

// QuerySpecificClusterModel: B=256 samples, n=64 points, d=768.
// Round 13: revert round-12's device-fence finalize (L2 writeback cost ~+9us
// on non-coherent XCD L2s) -> back to two kernels. Tail rewritten as
// register-resident Boruvka: same-mask via 6 ballots (no comp_s scans),
// hooking/doubling via __shfl (no ptr_s, no fences), ballot-prefix edge slots
// (no atomicAdd), label prop with pointer doubling (O(log n) not O(diam)),
// err-mask via ballots. Only remaining LDS in the MST loop: the two-stage
// per-comp atomicMin (proven exact tie-break). Gram identical to round 11.

#define NPTS 64
#define DIM 768
#define CH 128
#define NCH 6
#define NT 512
#define BIGF 1e9f
#define PGS 68

typedef __attribute__((ext_vector_type(8))) __bf16 bf16x8;
typedef __attribute__((ext_vector_type(4))) float f32x4;
typedef __attribute__((ext_vector_type(8))) unsigned short us8;

// cross-lane LDS visibility fence within one wave (guide rule #18)
__device__ __forceinline__ void lds_fence() {
  asm volatile("s_waitcnt lgkmcnt(0)" ::: "memory");
  __builtin_amdgcn_sched_barrier(0);
}

// ---- exact 3-way bf16 split: x == h + m + l ----
__device__ __forceinline__ void split3(float x, unsigned short& h,
                                       unsigned short& m, unsigned short& l) {
  unsigned u = __float_as_uint(x);
  unsigned rb = (u + 0x7FFFu + ((u >> 16) & 1u)) & 0xFFFF0000u;   // RNE
  h = (unsigned short)(rb >> 16);
  float r1 = x - __uint_as_float(rb);                              // exact
  unsigned u1 = __float_as_uint(r1);
  unsigned rb1 = (u1 + 0x7FFFu + ((u1 >> 16) & 1u)) & 0xFFFF0000u;
  m = (unsigned short)(rb1 >> 16);
  float r2 = r1 - __uint_as_float(rb1);                            // exact
  l = (unsigned short)(__float_as_uint(r2) >> 16);                 // exact
}

// 64-lane match mask of a 6-bit value held per-lane (6 ballots)
__device__ __forceinline__ unsigned long long match6(int v) {
  unsigned long long m = ~0ull;
  #pragma unroll
  for (int bb = 0; bb < 6; ++bb) {
    unsigned long long mb = __ballot(((v >> bb) & 1) != 0);
    m &= (((v >> bb) & 1) != 0) ? mb : ~mb;
  }
  return m;
}

// stage one chunk (scale by q, split3, swizzled LDS write). Hb = Hml[buf].
__device__ __forceinline__ void stage_chunk(
    unsigned short (*Hb)[NPTS][CH], const float4 (&pva)[2][2],
    const float4 (&qv)[2], int row0, int gran) {
  #pragma unroll
  for (int rr = 0; rr < 2; ++rr) {
    const int row = row0 + (rr << 5);
    float xs[8];
    xs[0] = pva[rr][0].x * qv[0].x; xs[1] = pva[rr][0].y * qv[0].y;
    xs[2] = pva[rr][0].z * qv[0].z; xs[3] = pva[rr][0].w * qv[0].w;
    xs[4] = pva[rr][1].x * qv[1].x; xs[5] = pva[rr][1].y * qv[1].y;
    xs[6] = pva[rr][1].z * qv[1].z; xs[7] = pva[rr][1].w * qv[1].w;
    us8 uh, um, ul;
    #pragma unroll
    for (int e = 0; e < 8; ++e) {
      unsigned short hh, mm, ll;
      split3(xs[e], hh, mm, ll);
      uh[e] = hh; um[e] = mm; ul[e] = ll;
    }
    const int p = gran ^ (row & 15);
    *reinterpret_cast<us8*>(&Hb[0][row][p << 3]) = uh;
    *reinterpret_cast<us8*>(&Hb[1][row][p << 3]) = um;
    *reinterpret_cast<us8*>(&Hb[2][row][p << 3]) = ul;
  }
}

// one chunk of MFMA work for this wave. Hb = Hml[buf].
__device__ __forceinline__ void mfma_chunk(
    const unsigned short (*Hb)[NPTS][CH], f32x4 (&acc)[2][2],
    int R, int C, int ksub, int lrow, int lhi) {
  #pragma unroll 1
  for (int ss = 0; ss < 2; ++ss) {
    const int s = ksub + (ss << 1);
    const int p = ((s << 2) + lhi) ^ lrow;
    bf16x8 fa[3][2], fb[3][2];
    #pragma unroll
    for (int v = 0; v < 3; ++v)
      #pragma unroll
      for (int tb = 0; tb < 2; ++tb) {
        const int row = (R << 5) + (tb << 4) + lrow;
        fa[v][tb] = *reinterpret_cast<const bf16x8*>(&Hb[v][row][p << 3]);
      }
    if (R != C) {
      #pragma unroll
      for (int v = 0; v < 3; ++v)
        #pragma unroll
        for (int tb = 0; tb < 2; ++tb) {
          const int row = (C << 5) + (tb << 4) + lrow;
          fb[v][tb] = *reinterpret_cast<const bf16x8*>(&Hb[v][row][p << 3]);
        }
    } else {
      #pragma unroll
      for (int v = 0; v < 3; ++v)
        #pragma unroll
        for (int tb = 0; tb < 2; ++tb) fb[v][tb] = fa[v][tb];
    }
    #pragma unroll
    for (int ti = 0; ti < 2; ++ti)
      #pragma unroll
      for (int tj = 0; tj < 2; ++tj) {
        acc[ti][tj] = __builtin_amdgcn_mfma_f32_16x16x32_bf16(fa[0][ti], fb[0][tj], acc[ti][tj], 0, 0, 0); // hh
        acc[ti][tj] = __builtin_amdgcn_mfma_f32_16x16x32_bf16(fa[0][ti], fb[1][tj], acc[ti][tj], 0, 0, 0); // hm
        acc[ti][tj] = __builtin_amdgcn_mfma_f32_16x16x32_bf16(fa[1][ti], fb[0][tj], acc[ti][tj], 0, 0, 0); // mh
        acc[ti][tj] = __builtin_amdgcn_mfma_f32_16x16x32_bf16(fa[1][ti], fb[1][tj], acc[ti][tj], 0, 0, 0); // mm
        acc[ti][tj] = __builtin_amdgcn_mfma_f32_16x16x32_bf16(fa[0][ti], fb[2][tj], acc[ti][tj], 0, 0, 0); // hl
        acc[ti][tj] = __builtin_amdgcn_mfma_f32_16x16x32_bf16(fa[2][ti], fb[0][tj], acc[ti][tj], 0, 0, 0); // lh
      }
  }
}

#define ISSUE_P(PV, cix) do {                                       \
    const int off_ = (cix) * CH;                                    \
    PV[0][0] = *(const float4*)(pr0 + off_);                        \
    PV[0][1] = *(const float4*)(pr0 + off_ + 4);                    \
    PV[1][0] = *(const float4*)(pr1 + off_);                        \
    PV[1][1] = *(const float4*)(pr1 + off_ + 4);                    \
  } while (0)

#define ISSUE_Q(QV, cix) do {                                       \
    const int off_ = (cix) * CH;                                    \
    QV[0] = *(const float4*)(qr + off_);                            \
    QV[1] = *(const float4*)(qr + off_ + 4);                        \
  } while (0)

// ============ fused kernel: MFMA Gram -> distances -> MST clustering ========
__global__ __launch_bounds__(NT) void fused_kernel(
    const float* __restrict__ q,      // [256,768]
    const float* __restrict__ psg,    // [256,64,768]
    const int*   __restrict__ labels, // [256,64]
    float* __restrict__ simS_o, float* __restrict__ disS_o,
    int* __restrict__ simC_o, int* __restrict__ errC_o)
{
  __shared__ __align__(16) unsigned short Hml[2][3][NPTS][CH]; // 96 KB dbuf
  __shared__ __align__(16) float PG[NPTS * PGS];
  __shared__ float diagf[NPTS];
  __shared__ unsigned bw_s[NPTS], bfl_s[NPTS];
  __shared__ int lab_s[NPTS];
  __shared__ __align__(8) unsigned long long ekey_s[NPTS];

  const int b = blockIdx.x;
  const int t = threadIdx.x;
  const int w = t >> 6;
  const int l = t & 63;

  const float* qb = q + (size_t)b * DIM;
  const float* pb = psg + (size_t)b * NPTS * DIM;

  const int row0 = t >> 4;
  const int gran = t & 15;
  const float* pr0 = pb + (size_t)row0 * DIM + (gran << 3);
  const float* pr1 = pr0 + 32 * DIM;
  const float* qr  = qb + (gran << 3);

  const int rw = w >> 1;
  const int R = rw >> 1, C = rw & 1;
  const int ksub = w & 1;
  const int lrow = l & 15;
  const int lhi  = l >> 4;

  f32x4 acc[2][2];
  {
    f32x4 z = {0.f, 0.f, 0.f, 0.f};
    acc[0][0] = z; acc[0][1] = z; acc[1][0] = z; acc[1][1] = z;
  }

  float4 pvaA[2][2], pvaB[2][2], qv[2];

  ISSUE_P(pvaA, 0);
  ISSUE_Q(qv, 0);
  ISSUE_P(pvaB, 1);
  stage_chunk(Hml[0], pvaA, qv, row0, gran);
  __syncthreads();

  #pragma unroll 1
  for (int cc = 0; cc < 3; ++cc) {
    if (cc < 2) ISSUE_P(pvaA, 2 * cc + 2);
    ISSUE_Q(qv, 2 * cc + 1);
    mfma_chunk(Hml[0], acc, R, C, ksub, lrow, lhi);
    stage_chunk(Hml[1], pvaB, qv, row0, gran);
    __syncthreads();
    if (cc < 2) {
      ISSUE_P(pvaB, 2 * cc + 3);
      ISSUE_Q(qv, 2 * cc + 2);
    }
    mfma_chunk(Hml[1], acc, R, C, ksub, lrow, lhi);
    if (cc < 2) stage_chunk(Hml[0], pvaA, qv, row0, gran);
    __syncthreads();
  }

  // ---- K-split pair reduce: odd wave -> LDS, even wave adds ----
  if (w & 1) {
    float* dst = PG + (rw << 10);
    #pragma unroll
    for (int ti = 0; ti < 2; ++ti)
      #pragma unroll
      for (int tj = 0; tj < 2; ++tj)
        *reinterpret_cast<f32x4*>(dst + (((ti << 1) + tj) << 8) + (l << 2)) = acc[ti][tj];
  }
  __syncthreads();
  if (!(w & 1)) {
    const float* src = PG + (rw << 10);
    #pragma unroll
    for (int ti = 0; ti < 2; ++ti)
      #pragma unroll
      for (int tj = 0; tj < 2; ++tj)
        acc[ti][tj] += *reinterpret_cast<const f32x4*>(src + (((ti << 1) + tj) << 8) + (l << 2));
  }
  __syncthreads();
  if (!(w & 1)) {
    #pragma unroll
    for (int ti = 0; ti < 2; ++ti)
      #pragma unroll
      for (int tj = 0; tj < 2; ++tj)
        #pragma unroll
        for (int reg = 0; reg < 4; ++reg) {
          const int grow = (R << 5) + (ti << 4) + (lhi << 2) + reg;
          const int gcol = (C << 5) + (tj << 4) + lrow;
          PG[grow * PGS + gcol] = acc[ti][tj][reg];
        }
  }
  __syncthreads();

  // ---- distances in place ----
  if (t < NPTS) diagf[t] = PG[t * PGS + t];
  __syncthreads();
  {
    const int r  = t >> 3;
    const int c0 = (t & 7) << 3;
    const float dr = diagf[r];
    #pragma unroll
    for (int e = 0; e < 8; ++e) {
      const int cc = c0 + e;
      const float gg = PG[r * PGS + cc];
      float d2 = dr + diagf[cc] - 2.f * gg;
      d2 = fmaxf(d2, 0.f);
      PG[r * PGS + cc] = (d2 > 0.f) ? sqrtf(d2) : 0.f;
    }
  }
  __syncthreads();
  if (w != 0) return;            // wave 0 runs the MST tail

  // ============== MST clustering (single wave, lane l = point l) ============
  float drow[64];
  #pragma unroll
  for (int v4 = 0; v4 < 16; ++v4) {
    f32x4 x = *reinterpret_cast<const f32x4*>(&PG[l * PGS + (v4 << 2)]);
    drow[v4 * 4 + 0] = x[0]; drow[v4 * 4 + 1] = x[1];
    drow[v4 * 4 + 2] = x[2]; drow[v4 * 4 + 3] = x[3];
  }
  int tl = labels[b * NPTS + l];

  unsigned long long sMask = 0ull;
  int kcnt = 0;
  #pragma unroll
  for (int v = 0; v < 8; ++v) {
    unsigned long long mv = __ballot(tl == v);
    kcnt += (mv != 0ull) ? 1 : 0;
    if (tl == v) sMask = mv;
  }
  int simC = __popcll(sMask);
  const int merges = NPTS - kcnt;

  float simS = 0.f, disS = 0.f;
  #pragma unroll
  for (int j = 0; j < NPTS; ++j) {
    bool sim = (sMask >> j) & 1ull;
    simS += sim ? drow[j] : 0.f;
    disS += sim ? 0.f : drow[j];
  }

  // ---- register-resident Boruvka ----
  unsigned long long same = 1ull << l;   // my component's member mask
  int repSlot = l;                       // min index of my component
  int ecnt = 0;                          // uniform edge count

  #pragma unroll 1
  for (int rd = 0; rd < 6; ++rd) {
    bw_s[l] = 0xFFFFFFFFu; bfl_s[l] = 0xFFFFFFFFu;
    lds_fence();
    // masked row argmin from registers (strict <: lowest j wins ties)
    float bv = BIGF; int bj = 64;
    #pragma unroll
    for (int j = 0; j < NPTS; ++j) {
      bool ok = !((same >> j) & 1ull) && (drow[j] < bv);
      bv = ok ? drow[j] : bv;
      bj = ok ? j : bj;
    }
    // per-comp min: two-stage exact lex (w bits, then flat)
    if (bj < 64) atomicMin(&bw_s[repSlot], __float_as_uint(bv));
    lds_fence();
    const unsigned bwc = bw_s[repSlot];
    if (bj < 64 && __float_as_uint(bv) == bwc)
      atomicMin(&bfl_s[repSlot], (unsigned)((l << 6) | bj));
    lds_fence();
    const unsigned rfl = bfl_s[repSlot];      // uniform within comp
    const bool valid = (bwc != 0xFFFFFFFFu);
    const int vpt = (int)(rfl & 63);          // other endpoint (point index)
    // hooking (register): root lane = repSlot lane
    const int otherRep = __shfl(repSlot, vpt);
    const bool isRoot = (l == repSlot);
    int ptr = repSlot;                        // non-roots follow their root
    if (isRoot && valid) ptr = otherRep;
    const int pd = __shfl(ptr, ptr);          // ptr of my target
    bool adder = false;
    if (isRoot && valid && ptr != l) {
      if (pd == l && l < ptr) ptr = l;        // mutual pair: smaller survives
      else adder = true;                      // this root records the edge
    }
    // edge slot via ballot prefix (deterministic, no atomics)
    const unsigned long long A = __ballot(adder);
    if (adder)
      ekey_s[ecnt + __popcll(A & ((1ull << l) - 1ull))] =
          ((unsigned long long)bwc << 12) | (unsigned long long)rfl;
    ecnt += (int)__popcll(A);
    // pointer doubling in registers (ballot exit)
    #pragma unroll 1
    for (int jj = 0; jj < 6; ++jj) {
      const int p2 = __shfl(ptr, ptr);
      if (__ballot(p2 != ptr) == 0ull) break;
      ptr = p2;
    }
    same = match6(ptr);                       // new component mask
    repSlot = __ffsll((long long)same) - 1;
    if (same == ~0ull) break;                 // single component
  }
  lds_fence();                                // ekey_s stores visible

  // ---- edge selection: keep the `merges` smallest (w, flat) keys ----
  const bool ehave = (l < ecnt);
  const unsigned long long my = ehave ? ekey_s[l] : ~0ull;
  int rank = 0;
  #pragma unroll 7
  for (int j = 0; j < 63; ++j) {
    unsigned long long kj = ekey_s[j];        // broadcast read
    rank += (j < ecnt && kj < my) ? 1 : 0;
  }
  const bool kept = ehave && (rank < merges);
  const int eu = (int)((my >> 6) & 63);
  const int ev = (int)(my & 63);

  // ---- label propagation: edge relax + pointer doubling ----
  lab_s[l] = l;
  lds_fence();
  #pragma unroll 1
  for (int iter = 0; iter < 64; ++iter) {
    int m = 0; bool ch = false;
    if (kept) {
      const int lu = lab_s[eu], lv = lab_s[ev];
      m = min(lu, lv);
      ch = (m < lu) || (m < lv);
    }
    if (ch) {
      atomicMin(&lab_s[eu], m);
      atomicMin(&lab_s[ev], m);
    }
    lds_fence();
    const int la = lab_s[l];
    const int lb = lab_s[la];                 // pointer doubling
    if (lb < la) lab_s[l] = lb;
    lds_fence();
    if (__ballot(ch) == 0ull) break;
  }
  const int cl = lab_s[l];

  // err count: cluster match-mask via 6 ballots (cl in 0..63)
  const unsigned long long cMask = match6(cl);
  int ec2 = __popcll(cMask ^ sMask);

  #pragma unroll
  for (int off = 32; off; off >>= 1) {
    simS += __shfl_xor(simS, off);
    disS += __shfl_xor(disS, off);
    simC += __shfl_xor(simC, off);
    ec2  += __shfl_xor(ec2, off);
  }
  if (l == 0) {
    simS_o[b] = simS; disS_o[b] = disS;
    simC_o[b] = simC; errC_o[b] = ec2;
  }
}

__global__ __launch_bounds__(64) void finalize_kernel(
    const float* __restrict__ simS, const float* __restrict__ disS,
    const int* __restrict__ simC, const int* __restrict__ errC,
    float* __restrict__ out)
{
  const int l = threadIdx.x;
  double ss = 0.0, dd = 0.0, sc = 0.0, ec = 0.0;
  #pragma unroll
  for (int r = 0; r < 4; ++r) {
    int i = (r << 6) + l;
    ss += (double)simS[i];
    dd += (double)disS[i];
    sc += (double)simC[i];
    ec += (double)errC[i];
  }
  #pragma unroll
  for (int off = 32; off; off >>= 1) {
    ss += __shfl_xor(ss, off);
    dd += __shfl_xor(dd, off);
    sc += __shfl_xor(sc, off);
    ec += __shfl_xor(ec, off);
  }
  if (l == 0) {
    const double total = 256.0 * 4096.0;
    double ms = ss / sc;
    double md = dd / (total - sc);
    out[0] = (float)(ec / 256.0 + 0.5 * (ms - md));
  }
}

extern "C" void kernel_launch(void* const* d_in, const int* in_sizes, int n_in,
                              void* d_out, int out_size, void* d_ws, size_t ws_size,
                              hipStream_t stream) {
  const float* q      = (const float*)d_in[0];
  const float* psg    = (const float*)d_in[1];
  const int*   labels = (const int*)d_in[2];
  float* out = (float*)d_out;

  float* simS = (float*)d_ws;          // [256]
  float* disS = simS + 256;            // [256]
  int*   simC = (int*)(disS + 256);    // [256]
  int*   errC = simC + 256;            // [256]

  fused_kernel<<<256, NT, 0, stream>>>(q, psg, labels, simS, disS, simC, errC);
  finalize_kernel<<<1, 64, 0, stream>>>(simS, disS, simC, errC, out);
}